// Round 5
// baseline (496.813 us; speedup 1.0000x reference)
//
#include <hip/hip_runtime.h>

// CFConv, round 9. Occupancy push:
//  - prefetch removed (round-8 lesson: +16 VGPR cost a block/CU, net -26%)
//  - edge LDS pool 34816 -> 26880 B by staging W2^T in two 64-row halves
//    through a [128][72] buffer (same pattern as W1): LDS now allows 6
//    blocks/CU; __launch_bounds__(256,5), grid 1280
//  - pipeline otherwise = round-7: k1 (node_linear|zero count|zero out),
//    hist, lookback scan, scatter->packed u64, edge_fused (sorted, segmented
//    reduce, fp32 atomics)

#define N_NODES 40000
#define N_EDGES 640000
#define IN_CH 128
#define OUT_CH 128
#define NUM_RBF 64

#define TILE_M 64
#define NTILES (N_EDGES / TILE_M)   // 10000
#define NB_NODE (N_NODES / TILE_M)  // 625
#define RBF_STR 72   // ushorts
#define T_STR 136    // ushorts
#define HV_STR 136   // ushorts
#define W_STR 72     // ushorts ([128][72] staging buffer for W1 and W2 halves)
#define W2_STR 136   // k1 only
#define NSCB ((N_NODES + 255) / 256)  // 157
#define EDGE_GRID 1280
#define K1_GRID 1024
#define ZC_BLOCKS 32
#define POOL_B 26880  // max(18432 W-staging, 17408 sHv + 9216 sRbf + 256 sAux)

typedef __attribute__((ext_vector_type(8))) short bf16x8;
typedef __attribute__((ext_vector_type(16))) float f32x16;

__device__ __forceinline__ unsigned short f2bf(float f) {
  unsigned u = __float_as_uint(f);
  return (unsigned short)((u + 0x7FFFu + ((u >> 16) & 1u)) >> 16);
}
__device__ __forceinline__ float bf2f(unsigned short s) {
  return __uint_as_float(((unsigned)s) << 16);
}

// ---------------------------------------------------------------------------
// K1: node_linear | zero(count) | zero(out)   (disjoint block ranges)
// ---------------------------------------------------------------------------
__global__ __launch_bounds__(256) void k1_kernel(
    const float* __restrict__ x, const float* __restrict__ Wl,
    const float* __restrict__ bl, unsigned short* __restrict__ hbf,
    int* __restrict__ count, float* __restrict__ outp) {
  __shared__ __align__(16) char pool[IN_CH * W2_STR * 2];  // 34816 B
  const int bid = blockIdx.x;
  const int t = threadIdx.x;

  if (bid >= NB_NODE) {
    if (bid < NB_NODE + ZC_BLOCKS) {
      if (count) {
        int4 z = {0, 0, 0, 0};
        for (int i = (bid - NB_NODE) * 256 + t; i < N_NODES / 4;
             i += ZC_BLOCKS * 256)
          ((int4*)count)[i] = z;
      }
    } else {
      if (outp) {
        float4 z = {0.f, 0.f, 0.f, 0.f};
        const int nb = K1_GRID - NB_NODE - ZC_BLOCKS;
        for (int i = (bid - NB_NODE - ZC_BLOCKS) * 256 + t;
             i < N_NODES * OUT_CH / 4; i += nb * 256)
          ((float4*)outp)[i] = z;
      }
    }
    return;
  }

  const int lane = t & 63;
  const int l31 = lane & 31;
  const int lhalf = lane >> 5;
  const int wv = t >> 6;
  const int nbase = wv * 32 + l31;

  {
    unsigned short* sWT = (unsigned short*)pool;
    const int k2 = t >> 1;
    const int d0 = (t & 1) * 64;
#pragma unroll
    for (int i = 0; i < 16; ++i) {
      float4 v = *(const float4*)(Wl + k2 * OUT_CH + d0 + 4 * i);
      sWT[(d0 + 4 * i + 0) * W2_STR + k2] = f2bf(v.x);
      sWT[(d0 + 4 * i + 1) * W2_STR + k2] = f2bf(v.y);
      sWT[(d0 + 4 * i + 2) * W2_STR + k2] = f2bf(v.z);
      sWT[(d0 + 4 * i + 3) * W2_STR + k2] = f2bf(v.w);
    }
  }
  __syncthreads();
  bf16x8 BW[8];
  {
    const unsigned short* sWT = (const unsigned short*)pool;
#pragma unroll
    for (int kk = 0; kk < 8; ++kk)
      BW[kk] = *(const bf16x8*)&sWT[nbase * W2_STR + kk * 16 + lhalf * 8];
  }
  const float blv = bl[nbase];
  __syncthreads();

  const int rbase = bid * TILE_M;
  unsigned short* sX = (unsigned short*)pool;
  {
    const int m = t >> 2;
    const int c0 = (t & 3) * 32;
    const float* src = x + (size_t)(rbase + m) * IN_CH + c0;
#pragma unroll
    for (int i = 0; i < 8; ++i) {
      float4 v = *(const float4*)(src + 4 * i);
      ushort4 p;
      p.x = f2bf(v.x); p.y = f2bf(v.y); p.z = f2bf(v.z); p.w = f2bf(v.w);
      *(ushort4*)&sX[m * T_STR + c0 + 4 * i] = p;
    }
  }
  __syncthreads();
#pragma unroll
  for (int mt = 0; mt < 2; ++mt) {
    f32x16 acc = {0.f, 0.f, 0.f, 0.f, 0.f, 0.f, 0.f, 0.f,
                  0.f, 0.f, 0.f, 0.f, 0.f, 0.f, 0.f, 0.f};
#pragma unroll
    for (int kk = 0; kk < 8; ++kk) {
      bf16x8 A = *(const bf16x8*)&sX[(mt * 32 + l31) * T_STR + kk * 16 + lhalf * 8];
      acc = __builtin_amdgcn_mfma_f32_32x32x16_bf16(A, BW[kk], acc, 0, 0, 0);
    }
#pragma unroll
    for (int r = 0; r < 16; ++r) {
      const int rowm = mt * 32 + (r & 3) + 8 * (r >> 2) + 4 * lhalf;
      hbf[(size_t)(rbase + rowm) * OUT_CH + nbase] = f2bf(acc[r] + blv);
    }
  }
}

// ---------------------------------------------------------------------------
// K2: histogram of dst + zero scan-status
// ---------------------------------------------------------------------------
__global__ void hist_kernel(const int* __restrict__ rowI, int* __restrict__ count,
                            unsigned long long* __restrict__ status) {
  if (blockIdx.x == 0 && threadIdx.x < NSCB) status[threadIdx.x] = 0ULL;
  int e = blockIdx.x * 256 + threadIdx.x;
  if (e < N_EDGES) atomicAdd(&count[rowI[e]], 1);
}

// ---------------------------------------------------------------------------
// K3: single-dispatch decoupled-lookback exclusive scan -> cursor
// ---------------------------------------------------------------------------
__global__ __launch_bounds__(256) void scan_kernel(
    const int* __restrict__ count, unsigned long long* __restrict__ status,
    int* __restrict__ cursor) {
  __shared__ int s[256];
  __shared__ int wsum[4];
  const int t = threadIdx.x;
  const int b = blockIdx.x;
  const int i = b * 256 + t;
  const int v = (i < N_NODES) ? count[i] : 0;
  s[t] = v;
  __syncthreads();
  for (int off = 1; off < 256; off <<= 1) {
    int u = (t >= off) ? s[t - off] : 0;
    __syncthreads();
    s[t] += u;
    __syncthreads();
  }
  if (t == 255)
    __hip_atomic_store(&status[b], (1ULL << 32) | (unsigned)s[255],
                       __ATOMIC_RELEASE, __HIP_MEMORY_SCOPE_AGENT);
  int contrib = 0;
  if (t < b) {  // b <= 156 < 255: one predecessor per thread
    unsigned long long sv;
    do {
      sv = __hip_atomic_load(&status[t], __ATOMIC_ACQUIRE,
                             __HIP_MEMORY_SCOPE_AGENT);
    } while (!(sv >> 32));
    contrib = (int)(unsigned)sv;
  }
  for (int o = 32; o > 0; o >>= 1) contrib += __shfl_down(contrib, o, 64);
  if ((t & 63) == 0) wsum[t >> 6] = contrib;
  __syncthreads();
  const int boffv = wsum[0] + wsum[1] + wsum[2] + wsum[3];
  if (i < N_NODES) cursor[i] = boffv + s[t] - v;
}

// ---------------------------------------------------------------------------
// K4: scatter -> packed u64: dst[51:36] | col[35:20] | e[19:0]
// ---------------------------------------------------------------------------
__global__ void scatter_kernel(const int* __restrict__ rowI,
                               const int* __restrict__ colI,
                               int* __restrict__ cursor,
                               unsigned long long* __restrict__ packed) {
  int e = blockIdx.x * 256 + threadIdx.x;
  if (e < N_EDGES) {
    const int r = rowI[e];
    const int c = colI[e];
    const int p = atomicAdd(&cursor[r], 1);
    packed[p] = ((unsigned long long)r << 36) | ((unsigned long long)c << 20) |
                (unsigned)e;
  }
}

// ---------------------------------------------------------------------------
// K5: fused filter + modulate + segmented reduce, sorted order.
// Small LDS pool (26880 B) -> 5-6 blocks/CU.
// ---------------------------------------------------------------------------
__global__ __launch_bounds__(256, 5) void edge_fused_kernel(
    const unsigned long long* __restrict__ packed, const float* __restrict__ rbf,
    const float* __restrict__ W1, const float* __restrict__ b1,
    const float* __restrict__ W2, const float* __restrict__ b2,
    const unsigned short* __restrict__ hbf, float* __restrict__ outp) {
  __shared__ __align__(16) char pool[POOL_B];  // 26880 B

  unsigned short* sHv = (unsigned short*)pool;                           // 17408
  unsigned short* sT = (unsigned short*)pool;                            // overlap
  unsigned short* sRbf = (unsigned short*)(pool + TILE_M * HV_STR * 2);  // 9216
  int* sAux = (int*)(pool + TILE_M * HV_STR * 2 + TILE_M * RBF_STR * 2); // 256

  const int t = threadIdx.x;
  const int lane = t & 63;
  const int l31 = lane & 31;
  const int lhalf = lane >> 5;
  const int wv = t >> 6;
  const int nbase = wv * 32 + l31;

  // ---- weight fragments via [128][72] staging buffer (3 passes) ----
  unsigned short* sWT = (unsigned short*)pool;
  const int kst = t >> 2;         // k row 0..63
  const int dst0 = (t & 3) * 32;  // d offset

  bf16x8 B1[4];
  bf16x8 B2[8];
  {
    // W1 (64x128)
#pragma unroll
    for (int i = 0; i < 8; ++i) {
      float4 v = *(const float4*)(W1 + kst * OUT_CH + dst0 + 4 * i);
      sWT[(dst0 + 4 * i + 0) * W_STR + kst] = f2bf(v.x);
      sWT[(dst0 + 4 * i + 1) * W_STR + kst] = f2bf(v.y);
      sWT[(dst0 + 4 * i + 2) * W_STR + kst] = f2bf(v.z);
      sWT[(dst0 + 4 * i + 3) * W_STR + kst] = f2bf(v.w);
    }
    __syncthreads();
#pragma unroll
    for (int kk = 0; kk < 4; ++kk)
      B1[kk] = *(const bf16x8*)&sWT[nbase * W_STR + kk * 16 + lhalf * 8];
    __syncthreads();
    // W2 rows 0..63
#pragma unroll
    for (int i = 0; i < 8; ++i) {
      float4 v = *(const float4*)(W2 + kst * OUT_CH + dst0 + 4 * i);
      sWT[(dst0 + 4 * i + 0) * W_STR + kst] = f2bf(v.x);
      sWT[(dst0 + 4 * i + 1) * W_STR + kst] = f2bf(v.y);
      sWT[(dst0 + 4 * i + 2) * W_STR + kst] = f2bf(v.z);
      sWT[(dst0 + 4 * i + 3) * W_STR + kst] = f2bf(v.w);
    }
    __syncthreads();
#pragma unroll
    for (int kk = 0; kk < 4; ++kk)
      B2[kk] = *(const bf16x8*)&sWT[nbase * W_STR + kk * 16 + lhalf * 8];
    __syncthreads();
    // W2 rows 64..127
#pragma unroll
    for (int i = 0; i < 8; ++i) {
      float4 v = *(const float4*)(W2 + (64 + kst) * OUT_CH + dst0 + 4 * i);
      sWT[(dst0 + 4 * i + 0) * W_STR + kst] = f2bf(v.x);
      sWT[(dst0 + 4 * i + 1) * W_STR + kst] = f2bf(v.y);
      sWT[(dst0 + 4 * i + 2) * W_STR + kst] = f2bf(v.z);
      sWT[(dst0 + 4 * i + 3) * W_STR + kst] = f2bf(v.w);
    }
    __syncthreads();
#pragma unroll
    for (int kk = 0; kk < 4; ++kk)
      B2[4 + kk] = *(const bf16x8*)&sWT[nbase * W_STR + kk * 16 + lhalf * 8];
  }
  const float b1v = b1[nbase];
  const float b2v = b2[nbase];

  const int m4 = t >> 2;        // rbf row this thread stages
  const int kq = (t & 3) * 16;  // rbf col quarter

  for (int tile = blockIdx.x; tile < NTILES; tile += gridDim.x) {
    const int ebase = tile * TILE_M;
    __syncthreads();  // (a) prev GEMM2's sT/sAux reads (or B2 reads) complete

    // ---- stage rbf (bf16, via packed edge id) + h rows -> sHv + dst ----
    {
      const unsigned long long pkm = packed[ebase + m4];
      const float* src = rbf + (size_t)(pkm & 0xFFFFFu) * NUM_RBF + kq;
#pragma unroll
      for (int i = 0; i < 4; ++i) {
        float4 v = *(const float4*)(src + 4 * i);
        ushort4 p;
        p.x = f2bf(v.x); p.y = f2bf(v.y); p.z = f2bf(v.z); p.w = f2bf(v.w);
        *(ushort4*)&sRbf[m4 * RBF_STR + kq + 4 * i] = p;
      }
      // 64 rows x 256B of hbf, 16B per thread-chunk, 4 chunks/thread
#pragma unroll
      for (int i = 0; i < 4; ++i) {
        const int chunk = t + 256 * i;
        const int row = chunk >> 4;
        const int c8 = (chunk & 15) * 8;  // ushort offset within row
        const int col = (int)((packed[ebase + row] >> 20) & 0xFFFFu);
        *(uint4*)&sHv[row * HV_STR + c8] =
            *(const uint4*)(hbf + (size_t)col * OUT_CH + c8);
      }
      if (t < TILE_M) sAux[t] = (int)(packed[ebase + t] >> 36);
    }
    __syncthreads();  // (b)

    // ---- h values from LDS (before sT overwrites sHv) ----
    float hv[2][16];
#pragma unroll
    for (int mt = 0; mt < 2; ++mt)
#pragma unroll
      for (int r = 0; r < 16; ++r) {
        const int rowm = mt * 32 + (r & 3) + 8 * (r >> 2) + 4 * lhalf;
        hv[mt][r] = bf2f(sHv[rowm * HV_STR + nbase]);
      }
    __syncthreads();  // (b2) sHv dead; sT may overwrite

    // ---- GEMM1: sT = bf16(relu(rbf @ W1 + b1)) ----
#pragma unroll
    for (int mt = 0; mt < 2; ++mt) {
      f32x16 acc = {0.f, 0.f, 0.f, 0.f, 0.f, 0.f, 0.f, 0.f,
                    0.f, 0.f, 0.f, 0.f, 0.f, 0.f, 0.f, 0.f};
#pragma unroll
      for (int kk = 0; kk < 4; ++kk) {
        bf16x8 A = *(const bf16x8*)&sRbf[(mt * 32 + l31) * RBF_STR + kk * 16 + lhalf * 8];
        acc = __builtin_amdgcn_mfma_f32_32x32x16_bf16(A, B1[kk], acc, 0, 0, 0);
      }
#pragma unroll
      for (int r = 0; r < 16; ++r) {
        const int rowm = (r & 3) + 8 * (r >> 2) + 4 * lhalf;
        float v = acc[r] + b1v;
        v = v > 0.f ? v : 0.f;
        sT[(mt * 32 + rowm) * T_STR + nbase] = f2bf(v);
      }
    }
    __syncthreads();  // (c)

    // ---- GEMM2 + modulate + in-register segmented reduce ----
    float sum = 0.f;
    int curd = -1;
#pragma unroll
    for (int mt = 0; mt < 2; ++mt) {
      f32x16 acc = {0.f, 0.f, 0.f, 0.f, 0.f, 0.f, 0.f, 0.f,
                    0.f, 0.f, 0.f, 0.f, 0.f, 0.f, 0.f, 0.f};
#pragma unroll
      for (int kk = 0; kk < 8; ++kk) {
        bf16x8 A = *(const bf16x8*)&sT[(mt * 32 + l31) * T_STR + kk * 16 + lhalf * 8];
        acc = __builtin_amdgcn_mfma_f32_32x32x16_bf16(A, B2[kk], acc, 0, 0, 0);
      }
#pragma unroll
      for (int r = 0; r < 16; ++r) {
        const int rowm = mt * 32 + (r & 3) + 8 * (r >> 2) + 4 * lhalf;
        const float m = hv[mt][r] * (acc[r] + b2v);
        const int d = sAux[rowm];
        if (d != curd) {
          if (curd >= 0) atomicAdd(&outp[(size_t)curd * OUT_CH + nbase], sum);
          curd = d;
          sum = m;
        } else {
          sum += m;
        }
      }
    }
    atomicAdd(&outp[(size_t)curd * OUT_CH + nbase], sum);
  }
}

// ---------------------------------------------------------------------------
// Fallback: natural-order edge kernel (ws too small)
// ---------------------------------------------------------------------------
__global__ __launch_bounds__(256, 5) void edge_atomic_kernel(
    const int* __restrict__ eidx, const float* __restrict__ rbf,
    const float* __restrict__ W1, const float* __restrict__ b1,
    const float* __restrict__ W2, const float* __restrict__ b2,
    const unsigned short* __restrict__ hbf, float* __restrict__ outp) {
  __shared__ __align__(16) char pool[POOL_B];

  unsigned short* sHv = (unsigned short*)pool;
  unsigned short* sT = (unsigned short*)pool;
  unsigned short* sRbf = (unsigned short*)(pool + TILE_M * HV_STR * 2);
  int* sAux = (int*)(pool + TILE_M * HV_STR * 2 + TILE_M * RBF_STR * 2);

  const int t = threadIdx.x;
  const int lane = t & 63;
  const int l31 = lane & 31;
  const int lhalf = lane >> 5;
  const int wv = t >> 6;
  const int nbase = wv * 32 + l31;

  unsigned short* sWT = (unsigned short*)pool;
  const int kst = t >> 2;
  const int dst0 = (t & 3) * 32;

  bf16x8 B1[4];
  bf16x8 B2[8];
  {
#pragma unroll
    for (int i = 0; i < 8; ++i) {
      float4 v = *(const float4*)(W1 + kst * OUT_CH + dst0 + 4 * i);
      sWT[(dst0 + 4 * i + 0) * W_STR + kst] = f2bf(v.x);
      sWT[(dst0 + 4 * i + 1) * W_STR + kst] = f2bf(v.y);
      sWT[(dst0 + 4 * i + 2) * W_STR + kst] = f2bf(v.z);
      sWT[(dst0 + 4 * i + 3) * W_STR + kst] = f2bf(v.w);
    }
    __syncthreads();
#pragma unroll
    for (int kk = 0; kk < 4; ++kk)
      B1[kk] = *(const bf16x8*)&sWT[nbase * W_STR + kk * 16 + lhalf * 8];
    __syncthreads();
#pragma unroll
    for (int i = 0; i < 8; ++i) {
      float4 v = *(const float4*)(W2 + kst * OUT_CH + dst0 + 4 * i);
      sWT[(dst0 + 4 * i + 0) * W_STR + kst] = f2bf(v.x);
      sWT[(dst0 + 4 * i + 1) * W_STR + kst] = f2bf(v.y);
      sWT[(dst0 + 4 * i + 2) * W_STR + kst] = f2bf(v.z);
      sWT[(dst0 + 4 * i + 3) * W_STR + kst] = f2bf(v.w);
    }
    __syncthreads();
#pragma unroll
    for (int kk = 0; kk < 4; ++kk)
      B2[kk] = *(const bf16x8*)&sWT[nbase * W_STR + kk * 16 + lhalf * 8];
    __syncthreads();
#pragma unroll
    for (int i = 0; i < 8; ++i) {
      float4 v = *(const float4*)(W2 + (64 + kst) * OUT_CH + dst0 + 4 * i);
      sWT[(dst0 + 4 * i + 0) * W_STR + kst] = f2bf(v.x);
      sWT[(dst0 + 4 * i + 1) * W_STR + kst] = f2bf(v.y);
      sWT[(dst0 + 4 * i + 2) * W_STR + kst] = f2bf(v.z);
      sWT[(dst0 + 4 * i + 3) * W_STR + kst] = f2bf(v.w);
    }
    __syncthreads();
#pragma unroll
    for (int kk = 0; kk < 4; ++kk)
      B2[4 + kk] = *(const bf16x8*)&sWT[nbase * W_STR + kk * 16 + lhalf * 8];
  }
  const float b1v = b1[nbase];
  const float b2v = b2[nbase];

  const int* rowI = eidx;
  const int* colI = eidx + N_EDGES;

  for (int tile = blockIdx.x; tile < NTILES; tile += gridDim.x) {
    const int ebase = tile * TILE_M;
    __syncthreads();
    {
      const int m = t >> 2;
      const int kq = (t & 3) * 16;
      const float* src = rbf + (size_t)(ebase + m) * NUM_RBF + kq;
#pragma unroll
      for (int i = 0; i < 4; ++i) {
        float4 v = *(const float4*)(src + 4 * i);
        ushort4 p;
        p.x = f2bf(v.x); p.y = f2bf(v.y); p.z = f2bf(v.z); p.w = f2bf(v.w);
        *(ushort4*)&sRbf[m * RBF_STR + kq + 4 * i] = p;
      }
#pragma unroll
      for (int i = 0; i < 4; ++i) {
        const int chunk = t + 256 * i;
        const int row = chunk >> 4;
        const int c8 = (chunk & 15) * 8;
        const int col = colI[ebase + row];
        *(uint4*)&sHv[row * HV_STR + c8] =
            *(const uint4*)(hbf + (size_t)col * OUT_CH + c8);
      }
      if (t < TILE_M) sAux[t] = rowI[ebase + t];
    }
    __syncthreads();

    float hv[2][16];
#pragma unroll
    for (int mt = 0; mt < 2; ++mt)
#pragma unroll
      for (int r = 0; r < 16; ++r) {
        const int rowm = mt * 32 + (r & 3) + 8 * (r >> 2) + 4 * lhalf;
        hv[mt][r] = bf2f(sHv[rowm * HV_STR + nbase]);
      }
    __syncthreads();

#pragma unroll
    for (int mt = 0; mt < 2; ++mt) {
      f32x16 acc = {0.f, 0.f, 0.f, 0.f, 0.f, 0.f, 0.f, 0.f,
                    0.f, 0.f, 0.f, 0.f, 0.f, 0.f, 0.f, 0.f};
#pragma unroll
      for (int kk = 0; kk < 4; ++kk) {
        bf16x8 A = *(const bf16x8*)&sRbf[(mt * 32 + l31) * RBF_STR + kk * 16 + lhalf * 8];
        acc = __builtin_amdgcn_mfma_f32_32x32x16_bf16(A, B1[kk], acc, 0, 0, 0);
      }
#pragma unroll
      for (int r = 0; r < 16; ++r) {
        const int rowm = (r & 3) + 8 * (r >> 2) + 4 * lhalf;
        float v = acc[r] + b1v;
        v = v > 0.f ? v : 0.f;
        sT[(mt * 32 + rowm) * T_STR + nbase] = f2bf(v);
      }
    }
    __syncthreads();

    float sum = 0.f;
    int curd = -1;
#pragma unroll
    for (int mt = 0; mt < 2; ++mt) {
      f32x16 acc = {0.f, 0.f, 0.f, 0.f, 0.f, 0.f, 0.f, 0.f,
                    0.f, 0.f, 0.f, 0.f, 0.f, 0.f, 0.f, 0.f};
#pragma unroll
      for (int kk = 0; kk < 8; ++kk) {
        bf16x8 A = *(const bf16x8*)&sT[(mt * 32 + l31) * T_STR + kk * 16 + lhalf * 8];
        acc = __builtin_amdgcn_mfma_f32_32x32x16_bf16(A, B2[kk], acc, 0, 0, 0);
      }
#pragma unroll
      for (int r = 0; r < 16; ++r) {
        const int rowm = mt * 32 + (r & 3) + 8 * (r >> 2) + 4 * lhalf;
        const float m = hv[mt][r] * (acc[r] + b2v);
        const int d = sAux[rowm];
        if (d != curd) {
          if (curd >= 0) atomicAdd(&outp[(size_t)curd * OUT_CH + nbase], sum);
          curd = d;
          sum = m;
        } else {
          sum += m;
        }
      }
    }
    atomicAdd(&outp[(size_t)curd * OUT_CH + nbase], sum);
  }
}

// ---------------------------------------------------------------------------
extern "C" void kernel_launch(void* const* d_in, const int* in_sizes, int n_in,
                              void* d_out, int out_size, void* d_ws, size_t ws_size,
                              hipStream_t stream) {
  const float* x    = (const float*)d_in[0];
  const int*   eidx = (const int*)d_in[1];
  const float* rbf  = (const float*)d_in[2];
  const float* W1   = (const float*)d_in[3];
  const float* b1   = (const float*)d_in[4];
  const float* W2   = (const float*)d_in[5];
  const float* b2   = (const float*)d_in[6];
  const float* Wl   = (const float*)d_in[7];
  const float* bl   = (const float*)d_in[8];
  float* out = (float*)d_out;

  char* ws = (char*)d_ws;
  const size_t HBF_B = (size_t)N_NODES * OUT_CH * 2;   // 10,240,000
  const size_t PK_B = (size_t)N_EDGES * 8;             //  5,120,000
  const size_t CNT_B = (size_t)N_NODES * 4;            //    160,000 (x2)
  const size_t ST_B = 1280;
  const size_t need = HBF_B + PK_B + 2 * CNT_B + ST_B + 64;

  size_t off = 0;
  unsigned short* hbf = (unsigned short*)(ws + off); off += HBF_B;
  unsigned long long* packed = (unsigned long long*)(ws + off); off += PK_B;
  int* count  = (int*)(ws + off); off += CNT_B;
  int* cursor = (int*)(ws + off); off += CNT_B;
  unsigned long long* status = (unsigned long long*)(ws + off); off += ST_B;

  const int* rowI = eidx;
  const int* colI = eidx + N_EDGES;

  if (ws_size >= need) {
    k1_kernel<<<K1_GRID, 256, 0, stream>>>(x, Wl, bl, hbf, count, out);
    hist_kernel<<<(N_EDGES + 255) / 256, 256, 0, stream>>>(rowI, count, status);
    scan_kernel<<<NSCB, 256, 0, stream>>>(count, status, cursor);
    scatter_kernel<<<(N_EDGES + 255) / 256, 256, 0, stream>>>(
        rowI, colI, cursor, packed);
    edge_fused_kernel<<<EDGE_GRID, 256, 0, stream>>>(
        packed, rbf, W1, b1, W2, b2, hbf, out);
  } else {
    hipMemsetAsync(out, 0, (size_t)N_NODES * OUT_CH * sizeof(float), stream);
    k1_kernel<<<NB_NODE, 256, 0, stream>>>(x, Wl, bl, hbf, nullptr, nullptr);
    edge_atomic_kernel<<<EDGE_GRID, 256, 0, stream>>>(
        eidx, rbf, W1, b1, W2, b2, hbf, out);
  }
}

// Round 6
// 413.853 us; speedup vs baseline: 1.2005x; 1.2005x over previous
//
#include <hip/hip_runtime.h>

// CFConv, round 10. Register-pressure attack via smaller tile:
//  - TILE_M 64 -> 32: halves per-thread live state (hv 16, acc 16, scan 16
//    rows) -> fits (256,4)'s 128-reg cap with slack; actual ~90 regs lets HW
//    run 5+ blocks/CU (launch_bounds only caps, residency is by actual usage)
//  - barrier (b2) removed: sT writes hit only the (rowm,nbase) cells the same
//    thread read for hv (column-partitioned) -> 3 barriers/tile
//  - aux: hipMemsetAsync(count+status), hist folded into k1 zero-out blocks
//  - lessons kept: no grid.sync (r6), no prefetch regs (r8), no (256,5) (r9)

#define N_NODES 40000
#define N_EDGES 640000
#define IN_CH 128
#define OUT_CH 128
#define NUM_RBF 64

#define TILE_M 32
#define NTILES (N_EDGES / TILE_M)   // 20000
#define NB_NODE (N_NODES / 64)      // 625 node-linear tiles (64-row)
#define RBF_STR 72   // ushorts
#define T_STR 136    // ushorts
#define HV_STR 136   // ushorts
#define W_STR 72     // [128][72] W staging
#define W2_STR 136   // k1 only
#define NSCB ((N_NODES + 255) / 256)  // 157
#define EDGE_GRID 1280
#define K1_GRID 1024
#define POOL_B 18432  // max(W staging 18432, 8704 sHv + 4608 sRbf + 128 sAux)

typedef __attribute__((ext_vector_type(8))) short bf16x8;
typedef __attribute__((ext_vector_type(16))) float f32x16;

__device__ __forceinline__ unsigned short f2bf(float f) {
  unsigned u = __float_as_uint(f);
  return (unsigned short)((u + 0x7FFFu + ((u >> 16) & 1u)) >> 16);
}
__device__ __forceinline__ float bf2f(unsigned short s) {
  return __uint_as_float(((unsigned)s) << 16);
}

// ---------------------------------------------------------------------------
// K1: node_linear (blk<625) | zero(out)+hist (blk>=625)
// ---------------------------------------------------------------------------
__global__ __launch_bounds__(256) void k1_kernel(
    const float* __restrict__ x, const float* __restrict__ Wl,
    const float* __restrict__ bl, unsigned short* __restrict__ hbf,
    const int* __restrict__ rowI, int* __restrict__ count,
    float* __restrict__ outp) {
  __shared__ __align__(16) char pool[IN_CH * W2_STR * 2];  // 34816 B
  const int bid = blockIdx.x;
  const int t = threadIdx.x;

  if (bid >= NB_NODE) {
    const int nb = K1_GRID - NB_NODE;
    if (outp) {
      float4 z = {0.f, 0.f, 0.f, 0.f};
      for (int i = (bid - NB_NODE) * 256 + t; i < N_NODES * OUT_CH / 4;
           i += nb * 256)
        ((float4*)outp)[i] = z;
    }
    if (count) {
      for (int e = (bid - NB_NODE) * 256 + t; e < N_EDGES; e += nb * 256)
        atomicAdd(&count[rowI[e]], 1);
    }
    return;
  }

  const int lane = t & 63;
  const int l31 = lane & 31;
  const int lhalf = lane >> 5;
  const int wv = t >> 6;
  const int nbase = wv * 32 + l31;

  {
    unsigned short* sWT = (unsigned short*)pool;
    const int k2 = t >> 1;
    const int d0 = (t & 1) * 64;
#pragma unroll
    for (int i = 0; i < 16; ++i) {
      float4 v = *(const float4*)(Wl + k2 * OUT_CH + d0 + 4 * i);
      sWT[(d0 + 4 * i + 0) * W2_STR + k2] = f2bf(v.x);
      sWT[(d0 + 4 * i + 1) * W2_STR + k2] = f2bf(v.y);
      sWT[(d0 + 4 * i + 2) * W2_STR + k2] = f2bf(v.z);
      sWT[(d0 + 4 * i + 3) * W2_STR + k2] = f2bf(v.w);
    }
  }
  __syncthreads();
  bf16x8 BW[8];
  {
    const unsigned short* sWT = (const unsigned short*)pool;
#pragma unroll
    for (int kk = 0; kk < 8; ++kk)
      BW[kk] = *(const bf16x8*)&sWT[nbase * W2_STR + kk * 16 + lhalf * 8];
  }
  const float blv = bl[nbase];
  __syncthreads();

  const int rbase = bid * 64;
  unsigned short* sX = (unsigned short*)pool;
  {
    const int m = t >> 2;
    const int c0 = (t & 3) * 32;
    const float* src = x + (size_t)(rbase + m) * IN_CH + c0;
#pragma unroll
    for (int i = 0; i < 8; ++i) {
      float4 v = *(const float4*)(src + 4 * i);
      ushort4 p;
      p.x = f2bf(v.x); p.y = f2bf(v.y); p.z = f2bf(v.z); p.w = f2bf(v.w);
      *(ushort4*)&sX[m * T_STR + c0 + 4 * i] = p;
    }
  }
  __syncthreads();
#pragma unroll
  for (int mt = 0; mt < 2; ++mt) {
    f32x16 acc = {0.f, 0.f, 0.f, 0.f, 0.f, 0.f, 0.f, 0.f,
                  0.f, 0.f, 0.f, 0.f, 0.f, 0.f, 0.f, 0.f};
#pragma unroll
    for (int kk = 0; kk < 8; ++kk) {
      bf16x8 A = *(const bf16x8*)&sX[(mt * 32 + l31) * T_STR + kk * 16 + lhalf * 8];
      acc = __builtin_amdgcn_mfma_f32_32x32x16_bf16(A, BW[kk], acc, 0, 0, 0);
    }
#pragma unroll
    for (int r = 0; r < 16; ++r) {
      const int rowm = mt * 32 + (r & 3) + 8 * (r >> 2) + 4 * lhalf;
      hbf[(size_t)(rbase + rowm) * OUT_CH + nbase] = f2bf(acc[r] + blv);
    }
  }
}

// ---------------------------------------------------------------------------
// K2: single-dispatch decoupled-lookback exclusive scan -> cursor
// ---------------------------------------------------------------------------
__global__ __launch_bounds__(256) void scan_kernel(
    const int* __restrict__ count, unsigned long long* __restrict__ status,
    int* __restrict__ cursor) {
  __shared__ int s[256];
  __shared__ int wsum[4];
  const int t = threadIdx.x;
  const int b = blockIdx.x;
  const int i = b * 256 + t;
  const int v = (i < N_NODES) ? count[i] : 0;
  s[t] = v;
  __syncthreads();
  for (int off = 1; off < 256; off <<= 1) {
    int u = (t >= off) ? s[t - off] : 0;
    __syncthreads();
    s[t] += u;
    __syncthreads();
  }
  if (t == 255)
    __hip_atomic_store(&status[b], (1ULL << 32) | (unsigned)s[255],
                       __ATOMIC_RELEASE, __HIP_MEMORY_SCOPE_AGENT);
  int contrib = 0;
  if (t < b) {  // b <= 156 < 255: one predecessor per thread
    unsigned long long sv;
    do {
      sv = __hip_atomic_load(&status[t], __ATOMIC_ACQUIRE,
                             __HIP_MEMORY_SCOPE_AGENT);
    } while (!(sv >> 32));
    contrib = (int)(unsigned)sv;
  }
  for (int o = 32; o > 0; o >>= 1) contrib += __shfl_down(contrib, o, 64);
  if ((t & 63) == 0) wsum[t >> 6] = contrib;
  __syncthreads();
  const int boffv = wsum[0] + wsum[1] + wsum[2] + wsum[3];
  if (i < N_NODES) cursor[i] = boffv + s[t] - v;
}

// ---------------------------------------------------------------------------
// K3: scatter -> packed u64: dst[51:36] | col[35:20] | e[19:0]
// ---------------------------------------------------------------------------
__global__ void scatter_kernel(const int* __restrict__ rowI,
                               const int* __restrict__ colI,
                               int* __restrict__ cursor,
                               unsigned long long* __restrict__ packed) {
  int e = blockIdx.x * 256 + threadIdx.x;
  if (e < N_EDGES) {
    const int r = rowI[e];
    const int c = colI[e];
    const int p = atomicAdd(&cursor[r], 1);
    packed[p] = ((unsigned long long)r << 36) | ((unsigned long long)c << 20) |
                (unsigned)e;
  }
}

// ---------------------------------------------------------------------------
// K4: fused filter + modulate + segmented reduce, sorted order, TILE_M=32.
// ---------------------------------------------------------------------------
__global__ __launch_bounds__(256, 4) void edge_fused_kernel(
    const unsigned long long* __restrict__ packed, const float* __restrict__ rbf,
    const float* __restrict__ W1, const float* __restrict__ b1,
    const float* __restrict__ W2, const float* __restrict__ b2,
    const unsigned short* __restrict__ hbf, float* __restrict__ outp) {
  __shared__ __align__(16) char pool[POOL_B];  // 18432 B

  unsigned short* sHv = (unsigned short*)pool;                           // 8704
  unsigned short* sT = (unsigned short*)pool;                            // overlap
  unsigned short* sRbf = (unsigned short*)(pool + TILE_M * HV_STR * 2);  // 4608
  int* sAux = (int*)(pool + TILE_M * HV_STR * 2 + TILE_M * RBF_STR * 2); // 128

  const int t = threadIdx.x;
  const int lane = t & 63;
  const int l31 = lane & 31;
  const int lhalf = lane >> 5;
  const int wv = t >> 6;
  const int nbase = wv * 32 + l31;

  // ---- weight fragments via [128][72] staging (3 passes, prologue only) ----
  unsigned short* sWT = (unsigned short*)pool;
  const int kst = t >> 2;
  const int dst0 = (t & 3) * 32;
  bf16x8 B1[4];
  bf16x8 B2[8];
  {
#pragma unroll
    for (int i = 0; i < 8; ++i) {
      float4 v = *(const float4*)(W1 + kst * OUT_CH + dst0 + 4 * i);
      sWT[(dst0 + 4 * i + 0) * W_STR + kst] = f2bf(v.x);
      sWT[(dst0 + 4 * i + 1) * W_STR + kst] = f2bf(v.y);
      sWT[(dst0 + 4 * i + 2) * W_STR + kst] = f2bf(v.z);
      sWT[(dst0 + 4 * i + 3) * W_STR + kst] = f2bf(v.w);
    }
    __syncthreads();
#pragma unroll
    for (int kk = 0; kk < 4; ++kk)
      B1[kk] = *(const bf16x8*)&sWT[nbase * W_STR + kk * 16 + lhalf * 8];
    __syncthreads();
#pragma unroll
    for (int i = 0; i < 8; ++i) {
      float4 v = *(const float4*)(W2 + kst * OUT_CH + dst0 + 4 * i);
      sWT[(dst0 + 4 * i + 0) * W_STR + kst] = f2bf(v.x);
      sWT[(dst0 + 4 * i + 1) * W_STR + kst] = f2bf(v.y);
      sWT[(dst0 + 4 * i + 2) * W_STR + kst] = f2bf(v.z);
      sWT[(dst0 + 4 * i + 3) * W_STR + kst] = f2bf(v.w);
    }
    __syncthreads();
#pragma unroll
    for (int kk = 0; kk < 4; ++kk)
      B2[kk] = *(const bf16x8*)&sWT[nbase * W_STR + kk * 16 + lhalf * 8];
    __syncthreads();
#pragma unroll
    for (int i = 0; i < 8; ++i) {
      float4 v = *(const float4*)(W2 + (64 + kst) * OUT_CH + dst0 + 4 * i);
      sWT[(dst0 + 4 * i + 0) * W_STR + kst] = f2bf(v.x);
      sWT[(dst0 + 4 * i + 1) * W_STR + kst] = f2bf(v.y);
      sWT[(dst0 + 4 * i + 2) * W_STR + kst] = f2bf(v.z);
      sWT[(dst0 + 4 * i + 3) * W_STR + kst] = f2bf(v.w);
    }
    __syncthreads();
#pragma unroll
    for (int kk = 0; kk < 4; ++kk)
      B2[4 + kk] = *(const bf16x8*)&sWT[nbase * W_STR + kk * 16 + lhalf * 8];
  }
  const float b1v = b1[nbase];
  const float b2v = b2[nbase];

  const int m8 = t >> 3;        // rbf row this thread stages (0..31)
  const int kq8 = (t & 7) * 8;  // rbf col offset

  for (int tile = blockIdx.x; tile < NTILES; tile += gridDim.x) {
    const int ebase = tile * TILE_M;
    __syncthreads();  // (a) prev GEMM2 sT/sAux reads (or B2 reads) complete

    // ---- stage rbf (bf16, via packed edge id) + h rows -> sHv + dst ----
    {
      const unsigned long long pkm = packed[ebase + m8];
      const float* src = rbf + (size_t)(pkm & 0xFFFFFu) * NUM_RBF + kq8;
      float4 v0 = *(const float4*)(src);
      float4 v1 = *(const float4*)(src + 4);
      ushort4 p;
      p.x = f2bf(v0.x); p.y = f2bf(v0.y); p.z = f2bf(v0.z); p.w = f2bf(v0.w);
      *(ushort4*)&sRbf[m8 * RBF_STR + kq8] = p;
      p.x = f2bf(v1.x); p.y = f2bf(v1.y); p.z = f2bf(v1.z); p.w = f2bf(v1.w);
      *(ushort4*)&sRbf[m8 * RBF_STR + kq8 + 4] = p;
      // 32 rows x 256B of hbf, 16B chunks, 2 chunks/thread
#pragma unroll
      for (int i = 0; i < 2; ++i) {
        const int chunk = t + 256 * i;
        const int row = chunk >> 4;
        const int c8 = (chunk & 15) * 8;
        const int col = (int)((packed[ebase + row] >> 20) & 0xFFFFu);
        *(uint4*)&sHv[row * HV_STR + c8] =
            *(const uint4*)(hbf + (size_t)col * OUT_CH + c8);
      }
      if (t < TILE_M) sAux[t] = (int)(packed[ebase + t] >> 36);
    }
    __syncthreads();  // (b)

    // ---- h values (each thread reads exactly the cells it later rewrites;
    //       columns are thread-partitioned -> no barrier needed after) ----
    float hv[16];
#pragma unroll
    for (int r = 0; r < 16; ++r) {
      const int rowm = (r & 3) + 8 * (r >> 2) + 4 * lhalf;
      hv[r] = bf2f(sHv[rowm * HV_STR + nbase]);
    }

    // ---- GEMM1: sT = bf16(relu(rbf @ W1 + b1)) ----
    {
      f32x16 acc = {0.f, 0.f, 0.f, 0.f, 0.f, 0.f, 0.f, 0.f,
                    0.f, 0.f, 0.f, 0.f, 0.f, 0.f, 0.f, 0.f};
#pragma unroll
      for (int kk = 0; kk < 4; ++kk) {
        bf16x8 A = *(const bf16x8*)&sRbf[l31 * RBF_STR + kk * 16 + lhalf * 8];
        acc = __builtin_amdgcn_mfma_f32_32x32x16_bf16(A, B1[kk], acc, 0, 0, 0);
      }
#pragma unroll
      for (int r = 0; r < 16; ++r) {
        const int rowm = (r & 3) + 8 * (r >> 2) + 4 * lhalf;
        float v = acc[r] + b1v;
        v = v > 0.f ? v : 0.f;
        sT[rowm * T_STR + nbase] = f2bf(v);
      }
    }
    __syncthreads();  // (c) sT complete before cross-column reads

    // ---- GEMM2 + modulate + in-register segmented reduce ----
    {
      f32x16 acc = {0.f, 0.f, 0.f, 0.f, 0.f, 0.f, 0.f, 0.f,
                    0.f, 0.f, 0.f, 0.f, 0.f, 0.f, 0.f, 0.f};
#pragma unroll
      for (int kk = 0; kk < 8; ++kk) {
        bf16x8 A = *(const bf16x8*)&sT[l31 * T_STR + kk * 16 + lhalf * 8];
        acc = __builtin_amdgcn_mfma_f32_32x32x16_bf16(A, B2[kk], acc, 0, 0, 0);
      }
      float sum = 0.f;
      int curd = -1;
#pragma unroll
      for (int r = 0; r < 16; ++r) {
        const int rowm = (r & 3) + 8 * (r >> 2) + 4 * lhalf;
        const float m = hv[r] * (acc[r] + b2v);
        const int d = sAux[rowm];
        if (d != curd) {
          if (curd >= 0) atomicAdd(&outp[(size_t)curd * OUT_CH + nbase], sum);
          curd = d;
          sum = m;
        } else {
          sum += m;
        }
      }
      atomicAdd(&outp[(size_t)curd * OUT_CH + nbase], sum);
    }
  }
}

// ---------------------------------------------------------------------------
// Fallback: natural-order edge kernel (ws too small)
// ---------------------------------------------------------------------------
__global__ __launch_bounds__(256, 4) void edge_atomic_kernel(
    const int* __restrict__ eidx, const float* __restrict__ rbf,
    const float* __restrict__ W1, const float* __restrict__ b1,
    const float* __restrict__ W2, const float* __restrict__ b2,
    const unsigned short* __restrict__ hbf, float* __restrict__ outp) {
  __shared__ __align__(16) char pool[POOL_B];

  unsigned short* sHv = (unsigned short*)pool;
  unsigned short* sT = (unsigned short*)pool;
  unsigned short* sRbf = (unsigned short*)(pool + TILE_M * HV_STR * 2);
  int* sAux = (int*)(pool + TILE_M * HV_STR * 2 + TILE_M * RBF_STR * 2);

  const int t = threadIdx.x;
  const int lane = t & 63;
  const int l31 = lane & 31;
  const int lhalf = lane >> 5;
  const int wv = t >> 6;
  const int nbase = wv * 32 + l31;

  unsigned short* sWT = (unsigned short*)pool;
  const int kst = t >> 2;
  const int dst0 = (t & 3) * 32;
  bf16x8 B1[4];
  bf16x8 B2[8];
  {
#pragma unroll
    for (int i = 0; i < 8; ++i) {
      float4 v = *(const float4*)(W1 + kst * OUT_CH + dst0 + 4 * i);
      sWT[(dst0 + 4 * i + 0) * W_STR + kst] = f2bf(v.x);
      sWT[(dst0 + 4 * i + 1) * W_STR + kst] = f2bf(v.y);
      sWT[(dst0 + 4 * i + 2) * W_STR + kst] = f2bf(v.z);
      sWT[(dst0 + 4 * i + 3) * W_STR + kst] = f2bf(v.w);
    }
    __syncthreads();
#pragma unroll
    for (int kk = 0; kk < 4; ++kk)
      B1[kk] = *(const bf16x8*)&sWT[nbase * W_STR + kk * 16 + lhalf * 8];
    __syncthreads();
#pragma unroll
    for (int i = 0; i < 8; ++i) {
      float4 v = *(const float4*)(W2 + kst * OUT_CH + dst0 + 4 * i);
      sWT[(dst0 + 4 * i + 0) * W_STR + kst] = f2bf(v.x);
      sWT[(dst0 + 4 * i + 1) * W_STR + kst] = f2bf(v.y);
      sWT[(dst0 + 4 * i + 2) * W_STR + kst] = f2bf(v.z);
      sWT[(dst0 + 4 * i + 3) * W_STR + kst] = f2bf(v.w);
    }
    __syncthreads();
#pragma unroll
    for (int kk = 0; kk < 4; ++kk)
      B2[kk] = *(const bf16x8*)&sWT[nbase * W_STR + kk * 16 + lhalf * 8];
    __syncthreads();
#pragma unroll
    for (int i = 0; i < 8; ++i) {
      float4 v = *(const float4*)(W2 + (64 + kst) * OUT_CH + dst0 + 4 * i);
      sWT[(dst0 + 4 * i + 0) * W_STR + kst] = f2bf(v.x);
      sWT[(dst0 + 4 * i + 1) * W_STR + kst] = f2bf(v.y);
      sWT[(dst0 + 4 * i + 2) * W_STR + kst] = f2bf(v.z);
      sWT[(dst0 + 4 * i + 3) * W_STR + kst] = f2bf(v.w);
    }
    __syncthreads();
#pragma unroll
    for (int kk = 0; kk < 4; ++kk)
      B2[4 + kk] = *(const bf16x8*)&sWT[nbase * W_STR + kk * 16 + lhalf * 8];
  }
  const float b1v = b1[nbase];
  const float b2v = b2[nbase];

  const int* rowI = eidx;
  const int* colI = eidx + N_EDGES;
  const int m8 = t >> 3;
  const int kq8 = (t & 7) * 8;

  for (int tile = blockIdx.x; tile < NTILES; tile += gridDim.x) {
    const int ebase = tile * TILE_M;
    __syncthreads();
    {
      const float* src = rbf + (size_t)(ebase + m8) * NUM_RBF + kq8;
      float4 v0 = *(const float4*)(src);
      float4 v1 = *(const float4*)(src + 4);
      ushort4 p;
      p.x = f2bf(v0.x); p.y = f2bf(v0.y); p.z = f2bf(v0.z); p.w = f2bf(v0.w);
      *(ushort4*)&sRbf[m8 * RBF_STR + kq8] = p;
      p.x = f2bf(v1.x); p.y = f2bf(v1.y); p.z = f2bf(v1.z); p.w = f2bf(v1.w);
      *(ushort4*)&sRbf[m8 * RBF_STR + kq8 + 4] = p;
#pragma unroll
      for (int i = 0; i < 2; ++i) {
        const int chunk = t + 256 * i;
        const int row = chunk >> 4;
        const int c8 = (chunk & 15) * 8;
        const int col = colI[ebase + row];
        *(uint4*)&sHv[row * HV_STR + c8] =
            *(const uint4*)(hbf + (size_t)col * OUT_CH + c8);
      }
      if (t < TILE_M) sAux[t] = rowI[ebase + t];
    }
    __syncthreads();

    float hv[16];
#pragma unroll
    for (int r = 0; r < 16; ++r) {
      const int rowm = (r & 3) + 8 * (r >> 2) + 4 * lhalf;
      hv[r] = bf2f(sHv[rowm * HV_STR + nbase]);
    }

    {
      f32x16 acc = {0.f, 0.f, 0.f, 0.f, 0.f, 0.f, 0.f, 0.f,
                    0.f, 0.f, 0.f, 0.f, 0.f, 0.f, 0.f, 0.f};
#pragma unroll
      for (int kk = 0; kk < 4; ++kk) {
        bf16x8 A = *(const bf16x8*)&sRbf[l31 * RBF_STR + kk * 16 + lhalf * 8];
        acc = __builtin_amdgcn_mfma_f32_32x32x16_bf16(A, B1[kk], acc, 0, 0, 0);
      }
#pragma unroll
      for (int r = 0; r < 16; ++r) {
        const int rowm = (r & 3) + 8 * (r >> 2) + 4 * lhalf;
        float v = acc[r] + b1v;
        v = v > 0.f ? v : 0.f;
        sT[rowm * T_STR + nbase] = f2bf(v);
      }
    }
    __syncthreads();

    {
      f32x16 acc = {0.f, 0.f, 0.f, 0.f, 0.f, 0.f, 0.f, 0.f,
                    0.f, 0.f, 0.f, 0.f, 0.f, 0.f, 0.f, 0.f};
#pragma unroll
      for (int kk = 0; kk < 8; ++kk) {
        bf16x8 A = *(const bf16x8*)&sT[l31 * T_STR + kk * 16 + lhalf * 8];
        acc = __builtin_amdgcn_mfma_f32_32x32x16_bf16(A, B2[kk], acc, 0, 0, 0);
      }
      float sum = 0.f;
      int curd = -1;
#pragma unroll
      for (int r = 0; r < 16; ++r) {
        const int rowm = (r & 3) + 8 * (r >> 2) + 4 * lhalf;
        const float m = hv[r] * (acc[r] + b2v);
        const int d = sAux[rowm];
        if (d != curd) {
          if (curd >= 0) atomicAdd(&outp[(size_t)curd * OUT_CH + nbase], sum);
          curd = d;
          sum = m;
        } else {
          sum += m;
        }
      }
      atomicAdd(&outp[(size_t)curd * OUT_CH + nbase], sum);
    }
  }
}

// ---------------------------------------------------------------------------
extern "C" void kernel_launch(void* const* d_in, const int* in_sizes, int n_in,
                              void* d_out, int out_size, void* d_ws, size_t ws_size,
                              hipStream_t stream) {
  const float* x    = (const float*)d_in[0];
  const int*   eidx = (const int*)d_in[1];
  const float* rbf  = (const float*)d_in[2];
  const float* W1   = (const float*)d_in[3];
  const float* b1   = (const float*)d_in[4];
  const float* W2   = (const float*)d_in[5];
  const float* b2   = (const float*)d_in[6];
  const float* Wl   = (const float*)d_in[7];
  const float* bl   = (const float*)d_in[8];
  float* out = (float*)d_out;

  char* ws = (char*)d_ws;
  const size_t HBF_B = (size_t)N_NODES * OUT_CH * 2;   // 10,240,000
  const size_t PK_B = (size_t)N_EDGES * 8;             //  5,120,000
  const size_t CNT_B = (size_t)N_NODES * 4;            //    160,000
  const size_t ST_B = 1280;
  const size_t need = HBF_B + PK_B + CNT_B + ST_B + CNT_B + 64;

  size_t off = 0;
  unsigned short* hbf = (unsigned short*)(ws + off); off += HBF_B;
  unsigned long long* packed = (unsigned long long*)(ws + off); off += PK_B;
  int* count = (int*)(ws + off); off += CNT_B;
  unsigned long long* status = (unsigned long long*)(ws + off); off += ST_B;
  int* cursor = (int*)(ws + off); off += CNT_B;

  const int* rowI = eidx;
  const int* colI = eidx + N_EDGES;

  if (ws_size >= need) {
    hipMemsetAsync(count, 0, CNT_B + ST_B, stream);  // count + status
    k1_kernel<<<K1_GRID, 256, 0, stream>>>(x, Wl, bl, hbf, rowI, count, out);
    scan_kernel<<<NSCB, 256, 0, stream>>>(count, status, cursor);
    scatter_kernel<<<(N_EDGES + 255) / 256, 256, 0, stream>>>(
        rowI, colI, cursor, packed);
    edge_fused_kernel<<<EDGE_GRID, 256, 0, stream>>>(
        packed, rbf, W1, b1, W2, b2, hbf, out);
  } else {
    hipMemsetAsync(out, 0, (size_t)N_NODES * OUT_CH * sizeof(float), stream);
    k1_kernel<<<NB_NODE, 256, 0, stream>>>(x, Wl, bl, hbf, rowI, nullptr,
                                           nullptr);
    edge_atomic_kernel<<<EDGE_GRID, 256, 0, stream>>>(
        eidx, rbf, W1, b1, W2, b2, hbf, out);
  }
}

// Round 7
// 400.233 us; speedup vs baseline: 1.2413x; 1.0340x over previous
//
#include <hip/hip_runtime.h>

// CFConv, round 11. Recombine verified-best pieces:
//  - edge body = round-1 (TILE_M=64, no prefetch, (256,4): 110us, VGPR 64)
//  - + round-9's 26880B pool (3-pass W staging) -> LDS allows 5 blocks/CU
//    (round-9's regression was ONLY the (256,5) VGPR cap, not the pool)
//  - barrier (b2) dropped: sT overlays sHv at the same stride; each thread
//    rewrites exactly the cells it read into hv -> thread-private RAW
//  - aux chain = round-10 (memset, k1 = node_linear | zero(out)+hist,
//    lookback scan, scatter -> packed u64)
//  - lessons: no grid.sync (r6), no reg prefetch (r8), no (256,5) (r9),
//    no TILE_M=32 (r10)

#define N_NODES 40000
#define N_EDGES 640000
#define IN_CH 128
#define OUT_CH 128
#define NUM_RBF 64

#define TILE_M 64
#define NTILES (N_EDGES / TILE_M)   // 10000
#define NB_NODE (N_NODES / 64)      // 625
#define RBF_STR 72   // ushorts
#define T_STR 136    // ushorts
#define HV_STR 136   // ushorts
#define W_STR 72     // [128][72] W staging
#define W2_STR 136   // k1 only
#define NSCB ((N_NODES + 255) / 256)  // 157
#define EDGE_GRID 1280
#define K1_GRID 1024
#define POOL_B 26880  // max(W staging 18432, 17408 sHv + 9216 sRbf + 256 sAux)

typedef __attribute__((ext_vector_type(8))) short bf16x8;
typedef __attribute__((ext_vector_type(16))) float f32x16;

__device__ __forceinline__ unsigned short f2bf(float f) {
  unsigned u = __float_as_uint(f);
  return (unsigned short)((u + 0x7FFFu + ((u >> 16) & 1u)) >> 16);
}
__device__ __forceinline__ float bf2f(unsigned short s) {
  return __uint_as_float(((unsigned)s) << 16);
}

// ---------------------------------------------------------------------------
// K1: node_linear (blk<625) | zero(out)+hist (blk>=625)
// ---------------------------------------------------------------------------
__global__ __launch_bounds__(256) void k1_kernel(
    const float* __restrict__ x, const float* __restrict__ Wl,
    const float* __restrict__ bl, unsigned short* __restrict__ hbf,
    const int* __restrict__ rowI, int* __restrict__ count,
    float* __restrict__ outp) {
  __shared__ __align__(16) char pool[IN_CH * W2_STR * 2];  // 34816 B
  const int bid = blockIdx.x;
  const int t = threadIdx.x;

  if (bid >= NB_NODE) {
    const int nb = K1_GRID - NB_NODE;
    if (outp) {
      float4 z = {0.f, 0.f, 0.f, 0.f};
      for (int i = (bid - NB_NODE) * 256 + t; i < N_NODES * OUT_CH / 4;
           i += nb * 256)
        ((float4*)outp)[i] = z;
    }
    if (count) {
      for (int e = (bid - NB_NODE) * 256 + t; e < N_EDGES; e += nb * 256)
        atomicAdd(&count[rowI[e]], 1);
    }
    return;
  }

  const int lane = t & 63;
  const int l31 = lane & 31;
  const int lhalf = lane >> 5;
  const int wv = t >> 6;
  const int nbase = wv * 32 + l31;

  {
    unsigned short* sWT = (unsigned short*)pool;
    const int k2 = t >> 1;
    const int d0 = (t & 1) * 64;
#pragma unroll
    for (int i = 0; i < 16; ++i) {
      float4 v = *(const float4*)(Wl + k2 * OUT_CH + d0 + 4 * i);
      sWT[(d0 + 4 * i + 0) * W2_STR + k2] = f2bf(v.x);
      sWT[(d0 + 4 * i + 1) * W2_STR + k2] = f2bf(v.y);
      sWT[(d0 + 4 * i + 2) * W2_STR + k2] = f2bf(v.z);
      sWT[(d0 + 4 * i + 3) * W2_STR + k2] = f2bf(v.w);
    }
  }
  __syncthreads();
  bf16x8 BW[8];
  {
    const unsigned short* sWT = (const unsigned short*)pool;
#pragma unroll
    for (int kk = 0; kk < 8; ++kk)
      BW[kk] = *(const bf16x8*)&sWT[nbase * W2_STR + kk * 16 + lhalf * 8];
  }
  const float blv = bl[nbase];
  __syncthreads();

  const int rbase = bid * 64;
  unsigned short* sX = (unsigned short*)pool;
  {
    const int m = t >> 2;
    const int c0 = (t & 3) * 32;
    const float* src = x + (size_t)(rbase + m) * IN_CH + c0;
#pragma unroll
    for (int i = 0; i < 8; ++i) {
      float4 v = *(const float4*)(src + 4 * i);
      ushort4 p;
      p.x = f2bf(v.x); p.y = f2bf(v.y); p.z = f2bf(v.z); p.w = f2bf(v.w);
      *(ushort4*)&sX[m * T_STR + c0 + 4 * i] = p;
    }
  }
  __syncthreads();
#pragma unroll
  for (int mt = 0; mt < 2; ++mt) {
    f32x16 acc = {0.f, 0.f, 0.f, 0.f, 0.f, 0.f, 0.f, 0.f,
                  0.f, 0.f, 0.f, 0.f, 0.f, 0.f, 0.f, 0.f};
#pragma unroll
    for (int kk = 0; kk < 8; ++kk) {
      bf16x8 A = *(const bf16x8*)&sX[(mt * 32 + l31) * T_STR + kk * 16 + lhalf * 8];
      acc = __builtin_amdgcn_mfma_f32_32x32x16_bf16(A, BW[kk], acc, 0, 0, 0);
    }
#pragma unroll
    for (int r = 0; r < 16; ++r) {
      const int rowm = mt * 32 + (r & 3) + 8 * (r >> 2) + 4 * lhalf;
      hbf[(size_t)(rbase + rowm) * OUT_CH + nbase] = f2bf(acc[r] + blv);
    }
  }
}

// ---------------------------------------------------------------------------
// K2: single-dispatch decoupled-lookback exclusive scan -> cursor
// ---------------------------------------------------------------------------
__global__ __launch_bounds__(256) void scan_kernel(
    const int* __restrict__ count, unsigned long long* __restrict__ status,
    int* __restrict__ cursor) {
  __shared__ int s[256];
  __shared__ int wsum[4];
  const int t = threadIdx.x;
  const int b = blockIdx.x;
  const int i = b * 256 + t;
  const int v = (i < N_NODES) ? count[i] : 0;
  s[t] = v;
  __syncthreads();
  for (int off = 1; off < 256; off <<= 1) {
    int u = (t >= off) ? s[t - off] : 0;
    __syncthreads();
    s[t] += u;
    __syncthreads();
  }
  if (t == 255)
    __hip_atomic_store(&status[b], (1ULL << 32) | (unsigned)s[255],
                       __ATOMIC_RELEASE, __HIP_MEMORY_SCOPE_AGENT);
  int contrib = 0;
  if (t < b) {  // b <= 156 < 255: one predecessor per thread
    unsigned long long sv;
    do {
      sv = __hip_atomic_load(&status[t], __ATOMIC_ACQUIRE,
                             __HIP_MEMORY_SCOPE_AGENT);
    } while (!(sv >> 32));
    contrib = (int)(unsigned)sv;
  }
  for (int o = 32; o > 0; o >>= 1) contrib += __shfl_down(contrib, o, 64);
  if ((t & 63) == 0) wsum[t >> 6] = contrib;
  __syncthreads();
  const int boffv = wsum[0] + wsum[1] + wsum[2] + wsum[3];
  if (i < N_NODES) cursor[i] = boffv + s[t] - v;
}

// ---------------------------------------------------------------------------
// K3: scatter -> packed u64: dst[51:36] | col[35:20] | e[19:0]
// ---------------------------------------------------------------------------
__global__ void scatter_kernel(const int* __restrict__ rowI,
                               const int* __restrict__ colI,
                               int* __restrict__ cursor,
                               unsigned long long* __restrict__ packed) {
  int e = blockIdx.x * 256 + threadIdx.x;
  if (e < N_EDGES) {
    const int r = rowI[e];
    const int c = colI[e];
    const int p = atomicAdd(&cursor[r], 1);
    packed[p] = ((unsigned long long)r << 36) | ((unsigned long long)c << 20) |
                (unsigned)e;
  }
}

// ---------------------------------------------------------------------------
// K4: fused filter + modulate + segmented reduce, sorted order, TILE_M=64.
// Pool 26880 B -> 5 blocks/CU by LDS; (256,4) keeps the round-1 reg budget.
// 3 barriers/tile (b2 dropped: sT rewrite is thread-private vs hv read).
// ---------------------------------------------------------------------------
__global__ __launch_bounds__(256, 4) void edge_fused_kernel(
    const unsigned long long* __restrict__ packed, const float* __restrict__ rbf,
    const float* __restrict__ W1, const float* __restrict__ b1,
    const float* __restrict__ W2, const float* __restrict__ b2,
    const unsigned short* __restrict__ hbf, float* __restrict__ outp) {
  __shared__ __align__(16) char pool[POOL_B];  // 26880 B

  unsigned short* sHv = (unsigned short*)pool;                           // 17408
  unsigned short* sT = (unsigned short*)pool;                            // overlap
  unsigned short* sRbf = (unsigned short*)(pool + TILE_M * HV_STR * 2);  // 9216
  int* sAux = (int*)(pool + TILE_M * HV_STR * 2 + TILE_M * RBF_STR * 2); // 256

  const int t = threadIdx.x;
  const int lane = t & 63;
  const int l31 = lane & 31;
  const int lhalf = lane >> 5;
  const int wv = t >> 6;
  const int nbase = wv * 32 + l31;

  // ---- weight fragments via [128][72] staging (3 passes, prologue only) ----
  unsigned short* sWT = (unsigned short*)pool;
  const int kst = t >> 2;
  const int dst0 = (t & 3) * 32;
  bf16x8 B1[4];
  bf16x8 B2[8];
  {
#pragma unroll
    for (int i = 0; i < 8; ++i) {
      float4 v = *(const float4*)(W1 + kst * OUT_CH + dst0 + 4 * i);
      sWT[(dst0 + 4 * i + 0) * W_STR + kst] = f2bf(v.x);
      sWT[(dst0 + 4 * i + 1) * W_STR + kst] = f2bf(v.y);
      sWT[(dst0 + 4 * i + 2) * W_STR + kst] = f2bf(v.z);
      sWT[(dst0 + 4 * i + 3) * W_STR + kst] = f2bf(v.w);
    }
    __syncthreads();
#pragma unroll
    for (int kk = 0; kk < 4; ++kk)
      B1[kk] = *(const bf16x8*)&sWT[nbase * W_STR + kk * 16 + lhalf * 8];
    __syncthreads();
#pragma unroll
    for (int i = 0; i < 8; ++i) {
      float4 v = *(const float4*)(W2 + kst * OUT_CH + dst0 + 4 * i);
      sWT[(dst0 + 4 * i + 0) * W_STR + kst] = f2bf(v.x);
      sWT[(dst0 + 4 * i + 1) * W_STR + kst] = f2bf(v.y);
      sWT[(dst0 + 4 * i + 2) * W_STR + kst] = f2bf(v.z);
      sWT[(dst0 + 4 * i + 3) * W_STR + kst] = f2bf(v.w);
    }
    __syncthreads();
#pragma unroll
    for (int kk = 0; kk < 4; ++kk)
      B2[kk] = *(const bf16x8*)&sWT[nbase * W_STR + kk * 16 + lhalf * 8];
    __syncthreads();
#pragma unroll
    for (int i = 0; i < 8; ++i) {
      float4 v = *(const float4*)(W2 + (64 + kst) * OUT_CH + dst0 + 4 * i);
      sWT[(dst0 + 4 * i + 0) * W_STR + kst] = f2bf(v.x);
      sWT[(dst0 + 4 * i + 1) * W_STR + kst] = f2bf(v.y);
      sWT[(dst0 + 4 * i + 2) * W_STR + kst] = f2bf(v.z);
      sWT[(dst0 + 4 * i + 3) * W_STR + kst] = f2bf(v.w);
    }
    __syncthreads();
#pragma unroll
    for (int kk = 0; kk < 4; ++kk)
      B2[4 + kk] = *(const bf16x8*)&sWT[nbase * W_STR + kk * 16 + lhalf * 8];
  }
  const float b1v = b1[nbase];
  const float b2v = b2[nbase];

  const int m4 = t >> 2;        // rbf row this thread stages
  const int kq = (t & 3) * 16;  // rbf col quarter

  for (int tile = blockIdx.x; tile < NTILES; tile += gridDim.x) {
    const int ebase = tile * TILE_M;
    __syncthreads();  // (a) prev GEMM2 sT/sAux reads (or B2 reads) complete

    // ---- stage rbf (bf16, via packed edge id) + h rows -> sHv + dst ----
    {
      const unsigned long long pkm = packed[ebase + m4];
      const float* src = rbf + (size_t)(pkm & 0xFFFFFu) * NUM_RBF + kq;
#pragma unroll
      for (int i = 0; i < 4; ++i) {
        float4 v = *(const float4*)(src + 4 * i);
        ushort4 p;
        p.x = f2bf(v.x); p.y = f2bf(v.y); p.z = f2bf(v.z); p.w = f2bf(v.w);
        *(ushort4*)&sRbf[m4 * RBF_STR + kq + 4 * i] = p;
      }
      // 64 rows x 256B of hbf, 16B per thread-chunk, 4 chunks/thread
#pragma unroll
      for (int i = 0; i < 4; ++i) {
        const int chunk = t + 256 * i;
        const int row = chunk >> 4;
        const int c8 = (chunk & 15) * 8;  // ushort offset within row
        const int col = (int)((packed[ebase + row] >> 20) & 0xFFFFu);
        *(uint4*)&sHv[row * HV_STR + c8] =
            *(const uint4*)(hbf + (size_t)col * OUT_CH + c8);
      }
      if (t < TILE_M) sAux[t] = (int)(packed[ebase + t] >> 36);
    }
    __syncthreads();  // (b)

    // ---- h values from LDS. GEMM1 below rewrites exactly these cells
    //      (same rows, same column nbase, same stride) -> thread-private
    //      RAW, no barrier needed between hv read and sT write. ----
    float hv[2][16];
#pragma unroll
    for (int mt = 0; mt < 2; ++mt)
#pragma unroll
      for (int r = 0; r < 16; ++r) {
        const int rowm = mt * 32 + (r & 3) + 8 * (r >> 2) + 4 * lhalf;
        hv[mt][r] = bf2f(sHv[rowm * HV_STR + nbase]);
      }

    // ---- GEMM1: sT = bf16(relu(rbf @ W1 + b1)) ----
#pragma unroll
    for (int mt = 0; mt < 2; ++mt) {
      f32x16 acc = {0.f, 0.f, 0.f, 0.f, 0.f, 0.f, 0.f, 0.f,
                    0.f, 0.f, 0.f, 0.f, 0.f, 0.f, 0.f, 0.f};
#pragma unroll
      for (int kk = 0; kk < 4; ++kk) {
        bf16x8 A = *(const bf16x8*)&sRbf[(mt * 32 + l31) * RBF_STR + kk * 16 + lhalf * 8];
        acc = __builtin_amdgcn_mfma_f32_32x32x16_bf16(A, B1[kk], acc, 0, 0, 0);
      }
#pragma unroll
      for (int r = 0; r < 16; ++r) {
        const int rowm = (r & 3) + 8 * (r >> 2) + 4 * lhalf;
        float v = acc[r] + b1v;
        v = v > 0.f ? v : 0.f;
        sT[(mt * 32 + rowm) * T_STR + nbase] = f2bf(v);
      }
    }
    __syncthreads();  // (c) sT complete before cross-column reads

    // ---- GEMM2 + modulate + in-register segmented reduce ----
    float sum = 0.f;
    int curd = -1;
#pragma unroll
    for (int mt = 0; mt < 2; ++mt) {
      f32x16 acc = {0.f, 0.f, 0.f, 0.f, 0.f, 0.f, 0.f, 0.f,
                    0.f, 0.f, 0.f, 0.f, 0.f, 0.f, 0.f, 0.f};
#pragma unroll
      for (int kk = 0; kk < 8; ++kk) {
        bf16x8 A = *(const bf16x8*)&sT[(mt * 32 + l31) * T_STR + kk * 16 + lhalf * 8];
        acc = __builtin_amdgcn_mfma_f32_32x32x16_bf16(A, B2[kk], acc, 0, 0, 0);
      }
#pragma unroll
      for (int r = 0; r < 16; ++r) {
        const int rowm = mt * 32 + (r & 3) + 8 * (r >> 2) + 4 * lhalf;
        const float m = hv[mt][r] * (acc[r] + b2v);
        const int d = sAux[rowm];
        if (d != curd) {
          if (curd >= 0) atomicAdd(&outp[(size_t)curd * OUT_CH + nbase], sum);
          curd = d;
          sum = m;
        } else {
          sum += m;
        }
      }
    }
    atomicAdd(&outp[(size_t)curd * OUT_CH + nbase], sum);
  }
}

// ---------------------------------------------------------------------------
// Fallback: natural-order edge kernel (ws too small)
// ---------------------------------------------------------------------------
__global__ __launch_bounds__(256, 4) void edge_atomic_kernel(
    const int* __restrict__ eidx, const float* __restrict__ rbf,
    const float* __restrict__ W1, const float* __restrict__ b1,
    const float* __restrict__ W2, const float* __restrict__ b2,
    const unsigned short* __restrict__ hbf, float* __restrict__ outp) {
  __shared__ __align__(16) char pool[POOL_B];

  unsigned short* sHv = (unsigned short*)pool;
  unsigned short* sT = (unsigned short*)pool;
  unsigned short* sRbf = (unsigned short*)(pool + TILE_M * HV_STR * 2);
  int* sAux = (int*)(pool + TILE_M * HV_STR * 2 + TILE_M * RBF_STR * 2);

  const int t = threadIdx.x;
  const int lane = t & 63;
  const int l31 = lane & 31;
  const int lhalf = lane >> 5;
  const int wv = t >> 6;
  const int nbase = wv * 32 + l31;

  unsigned short* sWT = (unsigned short*)pool;
  const int kst = t >> 2;
  const int dst0 = (t & 3) * 32;
  bf16x8 B1[4];
  bf16x8 B2[8];
  {
#pragma unroll
    for (int i = 0; i < 8; ++i) {
      float4 v = *(const float4*)(W1 + kst * OUT_CH + dst0 + 4 * i);
      sWT[(dst0 + 4 * i + 0) * W_STR + kst] = f2bf(v.x);
      sWT[(dst0 + 4 * i + 1) * W_STR + kst] = f2bf(v.y);
      sWT[(dst0 + 4 * i + 2) * W_STR + kst] = f2bf(v.z);
      sWT[(dst0 + 4 * i + 3) * W_STR + kst] = f2bf(v.w);
    }
    __syncthreads();
#pragma unroll
    for (int kk = 0; kk < 4; ++kk)
      B1[kk] = *(const bf16x8*)&sWT[nbase * W_STR + kk * 16 + lhalf * 8];
    __syncthreads();
#pragma unroll
    for (int i = 0; i < 8; ++i) {
      float4 v = *(const float4*)(W2 + kst * OUT_CH + dst0 + 4 * i);
      sWT[(dst0 + 4 * i + 0) * W_STR + kst] = f2bf(v.x);
      sWT[(dst0 + 4 * i + 1) * W_STR + kst] = f2bf(v.y);
      sWT[(dst0 + 4 * i + 2) * W_STR + kst] = f2bf(v.z);
      sWT[(dst0 + 4 * i + 3) * W_STR + kst] = f2bf(v.w);
    }
    __syncthreads();
#pragma unroll
    for (int kk = 0; kk < 4; ++kk)
      B2[kk] = *(const bf16x8*)&sWT[nbase * W_STR + kk * 16 + lhalf * 8];
    __syncthreads();
#pragma unroll
    for (int i = 0; i < 8; ++i) {
      float4 v = *(const float4*)(W2 + (64 + kst) * OUT_CH + dst0 + 4 * i);
      sWT[(dst0 + 4 * i + 0) * W_STR + kst] = f2bf(v.x);
      sWT[(dst0 + 4 * i + 1) * W_STR + kst] = f2bf(v.y);
      sWT[(dst0 + 4 * i + 2) * W_STR + kst] = f2bf(v.z);
      sWT[(dst0 + 4 * i + 3) * W_STR + kst] = f2bf(v.w);
    }
    __syncthreads();
#pragma unroll
    for (int kk = 0; kk < 4; ++kk)
      B2[4 + kk] = *(const bf16x8*)&sWT[nbase * W_STR + kk * 16 + lhalf * 8];
  }
  const float b1v = b1[nbase];
  const float b2v = b2[nbase];

  const int* rowI = eidx;
  const int* colI = eidx + N_EDGES;
  const int m4 = t >> 2;
  const int kq = (t & 3) * 16;

  for (int tile = blockIdx.x; tile < NTILES; tile += gridDim.x) {
    const int ebase = tile * TILE_M;
    __syncthreads();
    {
      const float* src = rbf + (size_t)(ebase + m4) * NUM_RBF + kq;
#pragma unroll
      for (int i = 0; i < 4; ++i) {
        float4 v = *(const float4*)(src + 4 * i);
        ushort4 p;
        p.x = f2bf(v.x); p.y = f2bf(v.y); p.z = f2bf(v.z); p.w = f2bf(v.w);
        *(ushort4*)&sRbf[m4 * RBF_STR + kq + 4 * i] = p;
      }
#pragma unroll
      for (int i = 0; i < 4; ++i) {
        const int chunk = t + 256 * i;
        const int row = chunk >> 4;
        const int c8 = (chunk & 15) * 8;
        const int col = colI[ebase + row];
        *(uint4*)&sHv[row * HV_STR + c8] =
            *(const uint4*)(hbf + (size_t)col * OUT_CH + c8);
      }
      if (t < TILE_M) sAux[t] = rowI[ebase + t];
    }
    __syncthreads();

    float hv[2][16];
#pragma unroll
    for (int mt = 0; mt < 2; ++mt)
#pragma unroll
      for (int r = 0; r < 16; ++r) {
        const int rowm = mt * 32 + (r & 3) + 8 * (r >> 2) + 4 * lhalf;
        hv[mt][r] = bf2f(sHv[rowm * HV_STR + nbase]);
      }

#pragma unroll
    for (int mt = 0; mt < 2; ++mt) {
      f32x16 acc = {0.f, 0.f, 0.f, 0.f, 0.f, 0.f, 0.f, 0.f,
                    0.f, 0.f, 0.f, 0.f, 0.f, 0.f, 0.f, 0.f};
#pragma unroll
      for (int kk = 0; kk < 4; ++kk) {
        bf16x8 A = *(const bf16x8*)&sRbf[(mt * 32 + l31) * RBF_STR + kk * 16 + lhalf * 8];
        acc = __builtin_amdgcn_mfma_f32_32x32x16_bf16(A, B1[kk], acc, 0, 0, 0);
      }
#pragma unroll
      for (int r = 0; r < 16; ++r) {
        const int rowm = (r & 3) + 8 * (r >> 2) + 4 * lhalf;
        float v = acc[r] + b1v;
        v = v > 0.f ? v : 0.f;
        sT[(mt * 32 + rowm) * T_STR + nbase] = f2bf(v);
      }
    }
    __syncthreads();

    float sum = 0.f;
    int curd = -1;
#pragma unroll
    for (int mt = 0; mt < 2; ++mt) {
      f32x16 acc = {0.f, 0.f, 0.f, 0.f, 0.f, 0.f, 0.f, 0.f,
                    0.f, 0.f, 0.f, 0.f, 0.f, 0.f, 0.f, 0.f};
#pragma unroll
      for (int kk = 0; kk < 8; ++kk) {
        bf16x8 A = *(const bf16x8*)&sT[(mt * 32 + l31) * T_STR + kk * 16 + lhalf * 8];
        acc = __builtin_amdgcn_mfma_f32_32x32x16_bf16(A, B2[kk], acc, 0, 0, 0);
      }
#pragma unroll
      for (int r = 0; r < 16; ++r) {
        const int rowm = mt * 32 + (r & 3) + 8 * (r >> 2) + 4 * lhalf;
        const float m = hv[mt][r] * (acc[r] + b2v);
        const int d = sAux[rowm];
        if (d != curd) {
          if (curd >= 0) atomicAdd(&outp[(size_t)curd * OUT_CH + nbase], sum);
          curd = d;
          sum = m;
        } else {
          sum += m;
        }
      }
    }
    atomicAdd(&outp[(size_t)curd * OUT_CH + nbase], sum);
  }
}

// ---------------------------------------------------------------------------
extern "C" void kernel_launch(void* const* d_in, const int* in_sizes, int n_in,
                              void* d_out, int out_size, void* d_ws, size_t ws_size,
                              hipStream_t stream) {
  const float* x    = (const float*)d_in[0];
  const int*   eidx = (const int*)d_in[1];
  const float* rbf  = (const float*)d_in[2];
  const float* W1   = (const float*)d_in[3];
  const float* b1   = (const float*)d_in[4];
  const float* W2   = (const float*)d_in[5];
  const float* b2   = (const float*)d_in[6];
  const float* Wl   = (const float*)d_in[7];
  const float* bl   = (const float*)d_in[8];
  float* out = (float*)d_out;

  char* ws = (char*)d_ws;
  const size_t HBF_B = (size_t)N_NODES * OUT_CH * 2;   // 10,240,000
  const size_t PK_B = (size_t)N_EDGES * 8;             //  5,120,000
  const size_t CNT_B = (size_t)N_NODES * 4;            //    160,000
  const size_t ST_B = 1280;
  const size_t need = HBF_B + PK_B + CNT_B + ST_B + CNT_B + 64;

  size_t off = 0;
  unsigned short* hbf = (unsigned short*)(ws + off); off += HBF_B;
  unsigned long long* packed = (unsigned long long*)(ws + off); off += PK_B;
  int* count = (int*)(ws + off); off += CNT_B;
  unsigned long long* status = (unsigned long long*)(ws + off); off += ST_B;
  int* cursor = (int*)(ws + off); off += CNT_B;

  const int* rowI = eidx;
  const int* colI = eidx + N_EDGES;

  if (ws_size >= need) {
    hipMemsetAsync(count, 0, CNT_B + ST_B, stream);  // count + status
    k1_kernel<<<K1_GRID, 256, 0, stream>>>(x, Wl, bl, hbf, rowI, count, out);
    scan_kernel<<<NSCB, 256, 0, stream>>>(count, status, cursor);
    scatter_kernel<<<(N_EDGES + 255) / 256, 256, 0, stream>>>(
        rowI, colI, cursor, packed);
    edge_fused_kernel<<<EDGE_GRID, 256, 0, stream>>>(
        packed, rbf, W1, b1, W2, b2, hbf, out);
  } else {
    hipMemsetAsync(out, 0, (size_t)N_NODES * OUT_CH * sizeof(float), stream);
    k1_kernel<<<NB_NODE, 256, 0, stream>>>(x, Wl, bl, hbf, rowI, nullptr,
                                           nullptr);
    edge_atomic_kernel<<<EDGE_GRID, 256, 0, stream>>>(
        eidx, rbf, W1, b1, W2, b2, hbf, out);
  }
}